// Round 4
// baseline (259.363 us; speedup 1.0000x reference)
//
#include <hip/hip_runtime.h>

// Problem: B=1, L=2048, DIM=16, HEADS=1, DIM_HEAD=1.
// softmax over size-1 heads axis == 1.0 -> attention all-ones, q,k dead.
// out[0,i,j,d] = v_i*W_out[d,0] + b_out[d] for ALL j; v_i = x[i,:].W_qkv[2,:].
// => 2048x16 row table broadcast into 256 MiB.
//
// v5: the true fillBuffer clone. Previous variants each kept one structural
// difference vs the 6.6 TB/s rocclr fill:
//   v0: load-free loop BUT comb-128KiB + 8192 waves
//   v2: flat sweep BUT in-loop loads + 8192 waves
//   v4: flat + low-occ BUT in-loop vmem load (vt[p>>13]) -- on CDNA loads and
//       stores share the in-order vmcnt queue; waiting on the load drains the
//       store stream, and at 1 wave/SIMD nothing hides it.
// v5 = single dispatch + 256x256 (1 wave/SIMD, fill-like) + per-block
// contiguous 1 MiB region + ZERO vmem ops in the store loop (8 row-values
// precomputed in registers from a 512 B broadcast read of x).

#define L_SEQ 2048
#define DIM 16
#define BLOCKS 256
#define THREADS 256
#define ROWS_PER_BLOCK (L_SEQ / BLOCKS)        // 8
#define F4_PER_ROW (L_SEQ * DIM / 4)           // 8192 float4 = 128 KiB
#define STORES_PER_ROW (F4_PER_ROW / THREADS)  // 32

typedef float f4 __attribute__((ext_vector_type(4)));

__global__ void __launch_bounds__(THREADS) fused_fill(
    const float* __restrict__ x,
    const float* __restrict__ W_qkv,
    const float* __restrict__ W_out,
    const float* __restrict__ b_out,
    f4* __restrict__ out) {
    const int b = blockIdx.x;   // owns rows 8b..8b+7 = contiguous 1 MiB of out
    const int t = threadIdx.x;
    const int dg = t & 3;       // this thread's d-group (f4 of the 16 dims)

    const f4 wo = ((const f4*)W_out)[dg];
    const f4 bo = ((const f4*)b_out)[dg];
    const f4* wv = (const f4*)(W_qkv + 2 * DIM);  // v-projection row
    const f4 w0 = wv[0], w1 = wv[1], w2 = wv[2], w3 = wv[3];

    // Prologue: all 256 threads redundantly compute the block's 8 row values
    // (reads 512 contiguous bytes of x, L1-broadcast; 8x4 packed FMAs).
    f4 val[ROWS_PER_BLOCK];
#pragma unroll
    for (int r = 0; r < ROWS_PER_BLOCK; ++r) {
        const f4* xi = (const f4*)(x + (size_t)(b * ROWS_PER_BLOCK + r) * DIM);
        f4 acc = xi[0] * w0 + xi[1] * w1 + xi[2] * w2 + xi[3] * w3;
        const float v = acc.x + acc.y + acc.z + acc.w;
        val[r] = v * wo + bo;   // static index, fully unrolled -> registers
    }

    // Store loop: 256 pure global_store_dwordx4, no vmem reads, no LDS, no
    // syncs, no vmcnt waits -- fire-and-forget like fillBuffer.
    // Row r, step k: f4 index r*8192 + k*256 + t; dg invariant (256%4==0).
    f4* base = out + (size_t)b * (ROWS_PER_BLOCK * F4_PER_ROW) + t;
#pragma unroll
    for (int r = 0; r < ROWS_PER_BLOCK; ++r) {
        f4* rowp = base + r * F4_PER_ROW;
        const f4 v = val[r];
#pragma unroll
        for (int k = 0; k < STORES_PER_ROW; ++k) {
            rowp[k * THREADS] = v;
        }
    }
}

extern "C" void kernel_launch(void* const* d_in, const int* in_sizes, int n_in,
                              void* d_out, int out_size, void* d_ws, size_t ws_size,
                              hipStream_t stream) {
    const float* x     = (const float*)d_in[0];  // (1, 2048, 16)
    const float* W_qkv = (const float*)d_in[1];  // (3, 16)
    const float* W_out = (const float*)d_in[2];  // (16, 1)
    const float* b_out = (const float*)d_in[3];  // (16,)

    fused_fill<<<BLOCKS, THREADS, 0, stream>>>(x, W_qkv, W_out, b_out,
                                               (f4*)d_out);
}